// Round 3
// baseline (788.107 us; speedup 1.0000x reference)
//
#include <hip/hip_runtime.h>
#include <hip/hip_bf16.h>

#define NN 32768
#define EE 524288
#define GG 512

typedef __bf16 bf16x8 __attribute__((ext_vector_type(8)));
typedef float  f32x4  __attribute__((ext_vector_type(4)));

static __device__ __forceinline__ float bf2f(unsigned short u) {
    union { unsigned int i; float f; } v; v.i = ((unsigned int)u) << 16; return v.f;
}
static __device__ __forceinline__ unsigned short f2bf(float f) {
    __bf16 b = (__bf16)f;
    return __builtin_bit_cast(unsigned short, b);
}

// ---------------- CSR build ----------------
__global__ void count_kernel(const int* __restrict__ src, int* __restrict__ cnt) {
    int e = blockIdx.x * 256 + threadIdx.x;
    if (e < EE) atomicAdd(&cnt[src[e]], 1);
}

// single block, 1024 threads; writes row_start AND cursor (init copy)
__global__ void scan_kernel(const int* __restrict__ cnt, int* __restrict__ row_start,
                            int* __restrict__ cursor) {
    int tid = threadIdx.x;
    int base = tid * 32;
    int vals[32];
    int s = 0;
    #pragma unroll
    for (int i = 0; i < 32; ++i) { vals[i] = cnt[base + i]; s += vals[i]; }
    int lane = tid & 63, wave = tid >> 6;
    int incl = s;
    #pragma unroll
    for (int off = 1; off < 64; off <<= 1) {
        int t = __shfl_up(incl, off);
        if (lane >= off) incl += t;
    }
    __shared__ int wave_tot[16];
    if (lane == 63) wave_tot[wave] = incl;
    __syncthreads();
    int wave_base = 0;
    for (int w = 0; w < wave; ++w) wave_base += wave_tot[w];
    int run = wave_base + incl - s;
    #pragma unroll
    for (int i = 0; i < 32; ++i) {
        row_start[base + i] = run;
        cursor[base + i] = run;
        run += vals[i];
    }
    if (tid == 1023) row_start[NN] = run;
}

__global__ void fill_kernel(const int* __restrict__ src, const int* __restrict__ dst,
                            const float* __restrict__ w,
                            int* __restrict__ cursor, int2* __restrict__ csr) {
    int e = blockIdx.x * 256 + threadIdx.x;
    if (e < EE) {
        int s = src[e];
        int p = atomicAdd(&cursor[s], 1);
        csr[p] = make_int2(dst[e], __float_as_int(w[e]));
    }
}

// ---------------- weight conversion: out[c*K+k] = bf16(in[k*128+c]) ----------------
struct WJob { const float* in; unsigned short* out; int K; };
struct WJobs { WJob j[10]; };

__global__ __launch_bounds__(256) void convert_w(WJobs jobs) {
    WJob jb = jobs.j[blockIdx.x >> 2];
    int quarter = blockIdx.x & 3;
    int tot = jb.K * 128;
    int per = tot / 4;
    for (int idx = quarter * per + threadIdx.x; idx < (quarter + 1) * per; idx += 256) {
        int k = idx >> 7, c = idx & 127;
        jb.out[c * jb.K + k] = f2bf(jb.in[idx]);
    }
}

// ---------------- fused GIN layer ----------------
// Block = 64 rows (nodes), 256 thr = 4 waves.
// Stage1: aggregate h2 = h + sum w*h[dst]  -> LDS A1 (bf16)
// Stage2: MFMA  T = relu(A1 @ W1 + b1)     -> LDS T (bf16)
// Stage3: MFMA  val = T @ W2 + b2; bn      -> global h_out (bf16 bn'd), LDS OUT (fp32)
// Stage4: segmented pool of OUT by graph   -> atomics into pools
template<int K1, bool POOL_BN, bool FIRST>
__global__ __launch_bounds__(256, 4) void layer_fused(
        const void* __restrict__ h_in,
        const int* __restrict__ row_start,
        const int2* __restrict__ csr,
        const unsigned short* __restrict__ W1t,   // [128][K1] bf16
        const float* __restrict__ b1,
        const unsigned short* __restrict__ W2t,   // [128][128] bf16
        const float* __restrict__ b2,
        const float* __restrict__ g, const float* __restrict__ be,
        const float* __restrict__ m, const float* __restrict__ v,
        const int* __restrict__ gidx,
        unsigned short* __restrict__ h_out,       // [N][128] bf16 (bn applied)
        float* __restrict__ pools, int col_off) {

    constexpr int A1W = K1 / 2 + 4;          // uints per A1 row (pad 16B)
    __shared__ unsigned int smem[8704];      // A1 | T, overlaid by OUT
    __shared__ int sgid[64];
    unsigned int* A1 = smem;
    unsigned int* T  = smem + 64 * A1W;
    float* OUT = (float*)smem;               // [64][132] fp32

    int tid = threadIdx.x;
    int wave = tid >> 6, lane = tid & 63;

    if (tid < 64) sgid[tid] = gidx[blockIdx.x * 64 + tid];

    // ---- stage 1: aggregation ----
    for (int i = 0; i < 16; ++i) {
        int r = wave * 16 + i;
        int node = blockIdx.x * 64 + r;
        int s = row_start[node], e = row_start[node + 1];
        if (FIRST) {
            const float* hp = (const float*)h_in;
            float acc0 = hp[(size_t)node * 64 + lane];
            for (int base = s; base < e; base += 64) {
                int n = e - base; if (n > 64) n = 64;
                int dj = 0, wb = 0;
                if (lane < n) { int2 ev = csr[base + lane]; dj = ev.x; wb = ev.y; }
                #pragma unroll 4
                for (int j = 0; j < n; ++j) {
                    int d = __shfl(dj, j);
                    float w = __int_as_float(__shfl(wb, j));
                    acc0 += w * hp[(size_t)d * 64 + lane];
                }
            }
            unsigned short me = f2bf(acc0);
            unsigned short ot = f2bf(__shfl_down(acc0, 1));
            if (!(lane & 1))
                A1[r * A1W + (lane >> 1)] = (unsigned int)me | ((unsigned int)ot << 16);
        } else {
            const unsigned int* hp = (const unsigned int*)h_in;
            unsigned int self = hp[(size_t)node * 64 + lane];
            float acc0 = bf2f((unsigned short)(self & 0xffff));
            float acc1 = bf2f((unsigned short)(self >> 16));
            for (int base = s; base < e; base += 64) {
                int n = e - base; if (n > 64) n = 64;
                int dj = 0, wb = 0;
                if (lane < n) { int2 ev = csr[base + lane]; dj = ev.x; wb = ev.y; }
                #pragma unroll 4
                for (int j = 0; j < n; ++j) {
                    int d = __shfl(dj, j);
                    float w = __int_as_float(__shfl(wb, j));
                    unsigned int hv = hp[(size_t)d * 64 + lane];
                    acc0 += w * bf2f((unsigned short)(hv & 0xffff));
                    acc1 += w * bf2f((unsigned short)(hv >> 16));
                }
            }
            A1[r * A1W + lane] = (unsigned int)f2bf(acc0) | ((unsigned int)f2bf(acc1) << 16);
        }
    }
    __syncthreads();

    // ---- stage 2: T = relu(A1 @ W1 + b1) ----
    constexpr int KS1 = K1 / 32;
    int mrow = lane & 15, quad = lane >> 4;
    int myrow = wave * 16 + mrow;

    bf16x8 a1[KS1];
    #pragma unroll
    for (int kk = 0; kk < KS1; ++kk)
        a1[kk] = *(const bf16x8*)(A1 + myrow * A1W + kk * 16 + quad * 4);

    f32x4 acc1[8];
    #pragma unroll
    for (int c = 0; c < 8; ++c) acc1[c] = (f32x4){0.f, 0.f, 0.f, 0.f};
    #pragma unroll
    for (int c = 0; c < 8; ++c) {
        const bf16x8* Brow = (const bf16x8*)(W1t + (size_t)(c * 16 + mrow) * K1);
        #pragma unroll
        for (int kk = 0; kk < KS1; ++kk)
            acc1[c] = __builtin_amdgcn_mfma_f32_16x16x32_bf16(a1[kk], Brow[kk * 4 + quad], acc1[c], 0, 0, 0);
    }

    unsigned short* Tp = (unsigned short*)T;
    int rowbase = wave * 16 + quad * 4;
    #pragma unroll
    for (int c = 0; c < 8; ++c) {
        float bv = b1[c * 16 + mrow];
        #pragma unroll
        for (int r = 0; r < 4; ++r) {
            float val = fmaxf(acc1[c][r] + bv, 0.f);
            Tp[(rowbase + r) * 136 + c * 16 + mrow] = f2bf(val);
        }
    }
    __syncthreads();

    // ---- stage 3: val = T @ W2 + b2 ----
    bf16x8 a2[4];
    #pragma unroll
    for (int kk = 0; kk < 4; ++kk)
        a2[kk] = *(const bf16x8*)(T + myrow * 68 + kk * 16 + quad * 4);

    f32x4 acc2[8];
    #pragma unroll
    for (int c = 0; c < 8; ++c) acc2[c] = (f32x4){0.f, 0.f, 0.f, 0.f};
    #pragma unroll
    for (int c = 0; c < 8; ++c) {
        const bf16x8* Brow = (const bf16x8*)(W2t + (size_t)(c * 16 + mrow) * 128);
        #pragma unroll
        for (int kk = 0; kk < 4; ++kk)
            acc2[c] = __builtin_amdgcn_mfma_f32_16x16x32_bf16(a2[kk], Brow[kk * 4 + quad], acc2[c], 0, 0, 0);
    }
    __syncthreads();   // all T reads done; OUT overlays A1/T

    #pragma unroll
    for (int c = 0; c < 8; ++c) {
        int ocol = c * 16 + mrow;
        float bv = b2[ocol];
        float scale = g[ocol] * rsqrtf(v[ocol] + 1e-3f);
        float shift = be[ocol] - m[ocol] * scale;
        #pragma unroll
        for (int r = 0; r < 4; ++r) {
            int rloc = rowbase + r;
            float val = acc2[c][r] + bv;
            float bnv = val * scale + shift;
            OUT[rloc * 132 + ocol] = POOL_BN ? bnv : val;
            float bnv2 = __shfl_down(bnv, 1);
            if (!(lane & 1)) {
                unsigned int pk = (unsigned int)f2bf(bnv) | ((unsigned int)f2bf(bnv2) << 16);
                *(unsigned int*)&h_out[(size_t)(blockIdx.x * 64 + rloc) * 128 + ocol] = pk;
            }
        }
    }
    __syncthreads();

    // ---- stage 4: segmented pool ----
    int col = tid & 127, half = tid >> 7;
    float acc = 0.f;
    int cur = sgid[half * 32];
    for (int r = half * 32; r < half * 32 + 32; ++r) {
        int gi = sgid[r];
        if (gi != cur) {
            atomicAdd(&pools[(size_t)cur * 640 + col_off + col], acc);
            acc = 0.f;
            cur = gi;
        }
        acc += OUT[r * 132 + col];
    }
    atomicAdd(&pools[(size_t)cur * 640 + col_off + col], acc);
}

// ---------------- fused readout ----------------
__global__ __launch_bounds__(128) void readout(const float* __restrict__ pools,
                                               const float* __restrict__ Wm1,
                                               const float* __restrict__ bm1,
                                               const float* __restrict__ Wm2,
                                               const float* __restrict__ bm2,
                                               float* __restrict__ out) {
    __shared__ float row[640];
    __shared__ float partial[4];
    int gb = blockIdx.x;
    for (int k = threadIdx.x; k < 640; k += 128) row[k] = pools[(size_t)gb * 640 + k];
    __syncthreads();
    int j = threadIdx.x;
    float acc = bm1[j];
    for (int k = 0; k < 640; ++k) acc += row[k] * Wm1[(size_t)k * 128 + j];
    acc = fmaxf(acc, 0.f);
    float p0 = acc * Wm2[j * 2], p1 = acc * Wm2[j * 2 + 1];
    #pragma unroll
    for (int off = 32; off; off >>= 1) { p0 += __shfl_down(p0, off); p1 += __shfl_down(p1, off); }
    int wave = j >> 6;
    if ((j & 63) == 0) { partial[wave * 2] = p0; partial[wave * 2 + 1] = p1; }
    __syncthreads();
    if (j == 0) {
        out[gb * 2]     = bm2[0] + partial[0] + partial[2];
        out[gb * 2 + 1] = bm2[1] + partial[1] + partial[3];
    }
}

extern "C" void kernel_launch(void* const* d_in, const int* in_sizes, int n_in,
                              void* d_out, int out_size, void* d_ws, size_t ws_size,
                              hipStream_t stream) {
    const float* x  = (const float*)d_in[0];
    const float* ew = (const float*)d_in[1];
    const float *W1[5], *b1[5], *W2[5], *b2[5];
    for (int l = 0; l < 5; ++l) {
        W1[l] = (const float*)d_in[2 + 4 * l];
        b1[l] = (const float*)d_in[3 + 4 * l];
        W2[l] = (const float*)d_in[4 + 4 * l];
        b2[l] = (const float*)d_in[5 + 4 * l];
    }
    const float *bg[3], *bb[3], *bm[3], *bv[3];
    for (int j = 0; j < 3; ++j) {
        bg[j] = (const float*)d_in[22 + 4 * j];
        bb[j] = (const float*)d_in[23 + 4 * j];
        bm[j] = (const float*)d_in[24 + 4 * j];
        bv[j] = (const float*)d_in[25 + 4 * j];
    }
    const float* Wm1 = (const float*)d_in[34];
    const float* bm1 = (const float*)d_in[35];
    const float* Wm2 = (const float*)d_in[36];
    const float* bm2 = (const float*)d_in[37];
    const int* edge_index = (const int*)d_in[38];
    const int* src = edge_index;
    const int* dst = edge_index + EE;
    const int* gidx = (const int*)d_in[39];

    char* p = (char*)d_ws;
    auto alloc = [&](size_t bytes) -> void* {
        void* r = (void*)p;
        p += (bytes + 255) & ~(size_t)255;
        return r;
    };
    int2*  csr       = (int2*)alloc((size_t)EE * 8);
    int*   row_start = (int*)alloc((NN + 1) * 4);
    int*   cnt       = (int*)alloc(NN * 4);
    int*   cursor    = (int*)alloc(NN * 4);
    unsigned short* hA = (unsigned short*)alloc((size_t)NN * 128 * 2);
    unsigned short* hB = (unsigned short*)alloc((size_t)NN * 128 * 2);
    float* pools = (float*)alloc((size_t)GG * 640 * 4);
    unsigned short* W1t[5], *W2t[5];
    for (int l = 0; l < 5; ++l) {
        W1t[l] = (unsigned short*)alloc((size_t)128 * 128 * 2);
        W2t[l] = (unsigned short*)alloc((size_t)128 * 128 * 2);
    }

    hipMemsetAsync(cnt, 0, NN * 4, stream);
    hipMemsetAsync(pools, 0, (size_t)GG * 640 * 4, stream);

    WJobs jobs;
    for (int l = 0; l < 5; ++l) {
        jobs.j[2 * l]     = WJob{W1[l], W1t[l], (l == 0) ? 64 : 128};
        jobs.j[2 * l + 1] = WJob{W2[l], W2t[l], 128};
    }
    convert_w<<<40, 256, 0, stream>>>(jobs);

    count_kernel<<<EE / 256, 256, 0, stream>>>(src, cnt);
    scan_kernel<<<1, 1024, 0, stream>>>(cnt, row_start, cursor);
    fill_kernel<<<EE / 256, 256, 0, stream>>>(src, dst, ew, cursor, csr);

    // bn applied AFTER layer l: {bn1, bn1, bn2, bn3, bn3}
    const int bnsel[5] = {0, 0, 1, 2, 2};

    layer_fused<64, false, true><<<NN / 64, 256, 0, stream>>>(
        x, row_start, csr, W1t[0], b1[0], W2t[0], b2[0],
        bg[0], bb[0], bm[0], bv[0], gidx, hA, pools, 0);

    const unsigned short* hin = hA;
    unsigned short* hout = hB;
    for (int l = 1; l < 5; ++l) {
        int s = bnsel[l];
        if (l < 4) {
            layer_fused<128, false, false><<<NN / 64, 256, 0, stream>>>(
                hin, row_start, csr, W1t[l], b1[l], W2t[l], b2[l],
                bg[s], bb[s], bm[s], bv[s], gidx, hout, pools, l * 128);
        } else {
            layer_fused<128, true, false><<<NN / 64, 256, 0, stream>>>(
                hin, row_start, csr, W1t[l], b1[l], W2t[l], b2[l],
                bg[s], bb[s], bm[s], bv[s], gidx, hout, pools, l * 128);
        }
        unsigned short* tmp = (unsigned short*)hin;
        hin = hout;
        hout = tmp;
    }

    readout<<<GG, 128, 0, stream>>>(pools, Wm1, bm1, Wm2, bm2, (float*)d_out);
}

// Round 4
// 507.248 us; speedup vs baseline: 1.5537x; 1.5537x over previous
//
#include <hip/hip_runtime.h>
#include <hip/hip_bf16.h>

#define NN 32768
#define EE 524288
#define GG 512

typedef __bf16 bf16x8 __attribute__((ext_vector_type(8)));
typedef float  f32x4  __attribute__((ext_vector_type(4)));

static __device__ __forceinline__ float bf2f(unsigned short u) {
    union { unsigned int i; float f; } v; v.i = ((unsigned int)u) << 16; return v.f;
}
static __device__ __forceinline__ unsigned short f2bf(float f) {
    __bf16 b = (__bf16)f;
    return __builtin_bit_cast(unsigned short, b);
}

// ---------------- CSR build ----------------
__global__ void count_kernel(const int* __restrict__ src, int* __restrict__ cnt) {
    int e = blockIdx.x * 256 + threadIdx.x;
    if (e < EE) atomicAdd(&cnt[src[e]], 1);
}

// single block, 1024 threads; writes row_start AND cursor
__global__ void scan_kernel(const int* __restrict__ cnt, int* __restrict__ row_start,
                            int* __restrict__ cursor) {
    int tid = threadIdx.x;
    int base = tid * 32;
    int vals[32];
    int s = 0;
    #pragma unroll
    for (int i = 0; i < 32; ++i) { vals[i] = cnt[base + i]; s += vals[i]; }
    int lane = tid & 63, wave = tid >> 6;
    int incl = s;
    #pragma unroll
    for (int off = 1; off < 64; off <<= 1) {
        int t = __shfl_up(incl, off);
        if (lane >= off) incl += t;
    }
    __shared__ int wave_tot[16];
    if (lane == 63) wave_tot[wave] = incl;
    __syncthreads();
    int wave_base = 0;
    for (int w = 0; w < wave; ++w) wave_base += wave_tot[w];
    int run = wave_base + incl - s;
    #pragma unroll
    for (int i = 0; i < 32; ++i) {
        row_start[base + i] = run;
        cursor[base + i] = run;
        run += vals[i];
    }
    if (tid == 1023) row_start[NN] = run;
}

// packed CSR entry: low16 = dst node (<32768), high16 = bf16(edge weight)
__global__ void fill_kernel(const int* __restrict__ src, const int* __restrict__ dst,
                            const float* __restrict__ w,
                            int* __restrict__ cursor, unsigned int* __restrict__ csr) {
    int e = blockIdx.x * 256 + threadIdx.x;
    if (e < EE) {
        int s = src[e];
        int p = atomicAdd(&cursor[s], 1);
        csr[p] = (unsigned int)dst[e] | ((unsigned int)f2bf(w[e]) << 16);
    }
}

// ---------------- weight conversion: out[c*K+k] = bf16(in[k*128+c]) ----------------
struct WJob { const float* in; unsigned short* out; int K; };
struct WJobs { WJob j[10]; };

__global__ __launch_bounds__(256) void convert_w(WJobs jobs) {
    WJob jb = jobs.j[blockIdx.x >> 2];
    int quarter = blockIdx.x & 3;
    int tot = jb.K * 128;
    int per = tot / 4;
    for (int idx = quarter * per + threadIdx.x; idx < (quarter + 1) * per; idx += 256) {
        int k = idx >> 7, c = idx & 127;
        jb.out[c * jb.K + k] = f2bf(jb.in[idx]);
    }
}

// ---------------- aggregation: one node per wave, 8192 blocks ----------------
// h2[i] = h[i] + sum_{e: src=i} w_e * h[dst_e]   (bf16 out)
template<bool FIRST>
__global__ __launch_bounds__(256) void aggregate(const void* __restrict__ h_in,
                                                 const int* __restrict__ row_start,
                                                 const unsigned int* __restrict__ csr,
                                                 unsigned short* __restrict__ h2) {
    int node = blockIdx.x * 4 + (threadIdx.x >> 6);
    int lane = threadIdx.x & 63;
    int s = row_start[node], e = row_start[node + 1];
    if (FIRST) {   // fp32 input [N][64]
        const float* hp = (const float*)h_in;
        float acc0 = hp[(size_t)node * 64 + lane];
        for (int base = s; base < e; base += 64) {
            int n = e - base; if (n > 64) n = 64;
            unsigned int ev = 0;
            if (lane < n) ev = csr[base + lane];
            #pragma unroll 8
            for (int j = 0; j < n; ++j) {
                unsigned int e2 = __shfl((int)ev, j);
                int d = e2 & 0xffff;
                float w = bf2f((unsigned short)(e2 >> 16));
                acc0 += w * hp[(size_t)d * 64 + lane];
            }
        }
        unsigned short me = f2bf(acc0);
        unsigned short ot = f2bf(__shfl_down(acc0, 1));
        if (!(lane & 1))
            ((unsigned int*)h2)[(size_t)node * 32 + (lane >> 1)] =
                (unsigned int)me | ((unsigned int)ot << 16);
    } else {       // bf16 input [N][128] viewed as uint[N][64]
        const unsigned int* hp = (const unsigned int*)h_in;
        unsigned int self = hp[(size_t)node * 64 + lane];
        float acc0 = bf2f((unsigned short)(self & 0xffff));
        float acc1 = bf2f((unsigned short)(self >> 16));
        for (int base = s; base < e; base += 64) {
            int n = e - base; if (n > 64) n = 64;
            unsigned int ev = 0;
            if (lane < n) ev = csr[base + lane];
            #pragma unroll 8
            for (int j = 0; j < n; ++j) {
                unsigned int e2 = __shfl((int)ev, j);
                int d = e2 & 0xffff;
                float w = bf2f((unsigned short)(e2 >> 16));
                unsigned int hv = hp[(size_t)d * 64 + lane];
                acc0 += w * bf2f((unsigned short)(hv & 0xffff));
                acc1 += w * bf2f((unsigned short)(hv >> 16));
            }
        }
        ((unsigned int*)h2)[(size_t)node * 64 + lane] =
            (unsigned int)f2bf(acc0) | ((unsigned int)f2bf(acc1) << 16);
    }
}

// ---------------- fused GEMM pair + BN + pool ----------------
// Block = 64 rows, 256 thr = 4 waves, each wave 16 rows x 128 cols.
// T = relu(A @ W1 + b1); val = T @ W2 + b2; h_out = bn(val); pool val (or bn for LAST).
template<int K1, bool LAST>
__global__ __launch_bounds__(256, 2) void gemm_pair(
        const unsigned short* __restrict__ h2,    // [N][K1] bf16
        const unsigned short* __restrict__ W1t,   // [128][K1] bf16
        const float* __restrict__ b1,
        const unsigned short* __restrict__ W2t,   // [128][128] bf16
        const float* __restrict__ b2,
        const float* __restrict__ g, const float* __restrict__ be,
        const float* __restrict__ m, const float* __restrict__ v,
        const int* __restrict__ gidx,
        unsigned short* __restrict__ h_out,       // [N][128] bf16 (bn applied)
        float* __restrict__ pools, int col_off) {

    constexpr int A1W = K1 / 2 + 4;              // uints per A row
    __shared__ unsigned int smem[8704];          // A1 | T, overlaid later by OUT
    __shared__ float sscale[128], sshift[128];
    __shared__ int sgid[64];
    unsigned int* A1 = smem;
    unsigned int* T  = smem + 64 * A1W;
    float* OUT = (float*)smem;                   // [64][132] fp32

    int tid = threadIdx.x;
    int wave = tid >> 6, lane = tid & 63;

    if (tid < 128) {
        float sc = g[tid] * rsqrtf(v[tid] + 1e-3f);
        sscale[tid] = sc;
        sshift[tid] = be[tid] - m[tid] * sc;
    } else if (tid < 192) {
        sgid[tid - 128] = gidx[blockIdx.x * 64 + (tid - 128)];
    }

    // ---- stage A from global (coalesced) ----
    {
        int row = tid >> 2, q = tid & 3;
        const uint4* srcp = (const uint4*)((const unsigned int*)h2 +
                            (size_t)(blockIdx.x * 64 + row) * (K1 / 2)) + q * (K1 / 32);
        uint4* dstp = (uint4*)(A1 + row * A1W) + q * (K1 / 32);
        #pragma unroll
        for (int i = 0; i < K1 / 32; ++i) dstp[i] = srcp[i];
    }
    __syncthreads();

    // ---- GEMM1: T = relu(A1 @ W1 + b1) ----
    constexpr int KS1 = K1 / 32;
    int mrow = lane & 15, quad = lane >> 4;
    int myrow = wave * 16 + mrow;

    bf16x8 a1[KS1];
    #pragma unroll
    for (int kk = 0; kk < KS1; ++kk)
        a1[kk] = *(const bf16x8*)(A1 + myrow * A1W + kk * 16 + quad * 4);

    f32x4 acc1[8];
    #pragma unroll
    for (int c = 0; c < 8; ++c) acc1[c] = (f32x4){0.f, 0.f, 0.f, 0.f};
    #pragma unroll
    for (int c = 0; c < 8; ++c) {
        const bf16x8* Brow = (const bf16x8*)(W1t + (size_t)(c * 16 + mrow) * K1);
        #pragma unroll
        for (int kk = 0; kk < KS1; ++kk)
            acc1[c] = __builtin_amdgcn_mfma_f32_16x16x32_bf16(a1[kk], Brow[kk * 4 + quad], acc1[c], 0, 0, 0);
    }

    unsigned short* Tp = (unsigned short*)T;
    int rowbase = wave * 16 + quad * 4;
    #pragma unroll
    for (int c = 0; c < 8; ++c) {
        float bv = b1[c * 16 + mrow];
        #pragma unroll
        for (int r = 0; r < 4; ++r) {
            float val = fmaxf(acc1[c][r] + bv, 0.f);
            Tp[(rowbase + r) * 136 + c * 16 + mrow] = f2bf(val);
        }
    }
    __syncthreads();

    // ---- GEMM2: val = T @ W2 + b2 ----
    bf16x8 a2[4];
    #pragma unroll
    for (int kk = 0; kk < 4; ++kk)
        a2[kk] = *(const bf16x8*)(T + myrow * 68 + kk * 16 + quad * 4);

    f32x4 acc2[8];
    #pragma unroll
    for (int c = 0; c < 8; ++c) acc2[c] = (f32x4){0.f, 0.f, 0.f, 0.f};
    #pragma unroll
    for (int c = 0; c < 8; ++c) {
        const bf16x8* Brow = (const bf16x8*)(W2t + (size_t)(c * 16 + mrow) * 128);
        #pragma unroll
        for (int kk = 0; kk < 4; ++kk)
            acc2[c] = __builtin_amdgcn_mfma_f32_16x16x32_bf16(a2[kk], Brow[kk * 4 + quad], acc2[c], 0, 0, 0);
    }
    __syncthreads();   // all T reads done; OUT overlays A1/T

    #pragma unroll
    for (int c = 0; c < 8; ++c) {
        float bv = b2[c * 16 + mrow];
        #pragma unroll
        for (int r = 0; r < 4; ++r)
            OUT[(rowbase + r) * 132 + c * 16 + mrow] = acc2[c][r] + bv;
    }
    __syncthreads();

    // ---- h_out = bn(val) (coalesced, skip for LAST) ----
    if (!LAST) {
        int row = tid >> 2, q = tid & 3;
        const f32x4* Op = (const f32x4*)(OUT + row * 132 + q * 32);
        unsigned int pk[16];
        #pragma unroll
        for (int i = 0; i < 8; ++i) {
            f32x4 vv = Op[i];
            int c0 = q * 32 + i * 4;
            float o0 = vv[0] * sscale[c0 + 0] + sshift[c0 + 0];
            float o1 = vv[1] * sscale[c0 + 1] + sshift[c0 + 1];
            float o2 = vv[2] * sscale[c0 + 2] + sshift[c0 + 2];
            float o3 = vv[3] * sscale[c0 + 3] + sshift[c0 + 3];
            pk[i * 2]     = (unsigned int)f2bf(o0) | ((unsigned int)f2bf(o1) << 16);
            pk[i * 2 + 1] = (unsigned int)f2bf(o2) | ((unsigned int)f2bf(o3) << 16);
        }
        uint4* dstp = (uint4*)(h_out + (size_t)(blockIdx.x * 64 + row) * 128 + q * 32);
        #pragma unroll
        for (int i = 0; i < 4; ++i)
            dstp[i] = make_uint4(pk[i * 4], pk[i * 4 + 1], pk[i * 4 + 2], pk[i * 4 + 3]);
    }

    // ---- segmented pool ----
    {
        int col = tid & 127, half = tid >> 7;
        float sc = LAST ? sscale[col] : 1.f;
        float sh = LAST ? sshift[col] : 0.f;
        float acc = 0.f;
        int cur = sgid[half * 32];
        for (int r = half * 32; r < half * 32 + 32; ++r) {
            int gi = sgid[r];
            if (gi != cur) {
                atomicAdd(&pools[(size_t)cur * 640 + col_off + col], acc);
                acc = 0.f;
                cur = gi;
            }
            float val = OUT[r * 132 + col];
            acc += LAST ? (val * sc + sh) : val;
        }
        atomicAdd(&pools[(size_t)cur * 640 + col_off + col], acc);
    }
}

// ---------------- fused readout ----------------
__global__ __launch_bounds__(128) void readout(const float* __restrict__ pools,
                                               const float* __restrict__ Wm1,
                                               const float* __restrict__ bm1,
                                               const float* __restrict__ Wm2,
                                               const float* __restrict__ bm2,
                                               float* __restrict__ out) {
    __shared__ float row[640];
    __shared__ float partial[4];
    int gb = blockIdx.x;
    for (int k = threadIdx.x; k < 640; k += 128) row[k] = pools[(size_t)gb * 640 + k];
    __syncthreads();
    int j = threadIdx.x;
    float acc = bm1[j];
    for (int k = 0; k < 640; ++k) acc += row[k] * Wm1[(size_t)k * 128 + j];
    acc = fmaxf(acc, 0.f);
    float p0 = acc * Wm2[j * 2], p1 = acc * Wm2[j * 2 + 1];
    #pragma unroll
    for (int off = 32; off; off >>= 1) { p0 += __shfl_down(p0, off); p1 += __shfl_down(p1, off); }
    int wave = j >> 6;
    if ((j & 63) == 0) { partial[wave * 2] = p0; partial[wave * 2 + 1] = p1; }
    __syncthreads();
    if (j == 0) {
        out[gb * 2]     = bm2[0] + partial[0] + partial[2];
        out[gb * 2 + 1] = bm2[1] + partial[1] + partial[3];
    }
}

extern "C" void kernel_launch(void* const* d_in, const int* in_sizes, int n_in,
                              void* d_out, int out_size, void* d_ws, size_t ws_size,
                              hipStream_t stream) {
    const float* x  = (const float*)d_in[0];
    const float* ew = (const float*)d_in[1];
    const float *W1[5], *b1[5], *W2[5], *b2[5];
    for (int l = 0; l < 5; ++l) {
        W1[l] = (const float*)d_in[2 + 4 * l];
        b1[l] = (const float*)d_in[3 + 4 * l];
        W2[l] = (const float*)d_in[4 + 4 * l];
        b2[l] = (const float*)d_in[5 + 4 * l];
    }
    const float *bg[3], *bb[3], *bm[3], *bv[3];
    for (int j = 0; j < 3; ++j) {
        bg[j] = (const float*)d_in[22 + 4 * j];
        bb[j] = (const float*)d_in[23 + 4 * j];
        bm[j] = (const float*)d_in[24 + 4 * j];
        bv[j] = (const float*)d_in[25 + 4 * j];
    }
    const float* Wm1 = (const float*)d_in[34];
    const float* bm1 = (const float*)d_in[35];
    const float* Wm2 = (const float*)d_in[36];
    const float* bm2 = (const float*)d_in[37];
    const int* edge_index = (const int*)d_in[38];
    const int* src = edge_index;
    const int* dst = edge_index + EE;
    const int* gidx = (const int*)d_in[39];

    char* p = (char*)d_ws;
    auto alloc = [&](size_t bytes) -> void* {
        void* r = (void*)p;
        p += (bytes + 255) & ~(size_t)255;
        return r;
    };
    unsigned int* csr = (unsigned int*)alloc((size_t)EE * 4);
    int* row_start    = (int*)alloc((NN + 1) * 4);
    int* cnt          = (int*)alloc(NN * 4);
    int* cursor       = (int*)alloc(NN * 4);
    unsigned short* h2buf = (unsigned short*)alloc((size_t)NN * 128 * 2);
    unsigned short* hA    = (unsigned short*)alloc((size_t)NN * 128 * 2);
    unsigned short* hB    = (unsigned short*)alloc((size_t)NN * 128 * 2);
    float* pools = (float*)alloc((size_t)GG * 640 * 4);
    unsigned short* W1t[5], *W2t[5];
    for (int l = 0; l < 5; ++l) {
        W1t[l] = (unsigned short*)alloc((size_t)128 * 128 * 2);
        W2t[l] = (unsigned short*)alloc((size_t)128 * 128 * 2);
    }

    hipMemsetAsync(cnt, 0, NN * 4, stream);
    hipMemsetAsync(pools, 0, (size_t)GG * 640 * 4, stream);

    WJobs jobs;
    for (int l = 0; l < 5; ++l) {
        jobs.j[2 * l]     = WJob{W1[l], W1t[l], (l == 0) ? 64 : 128};
        jobs.j[2 * l + 1] = WJob{W2[l], W2t[l], 128};
    }
    convert_w<<<40, 256, 0, stream>>>(jobs);

    count_kernel<<<EE / 256, 256, 0, stream>>>(src, cnt);
    scan_kernel<<<1, 1024, 0, stream>>>(cnt, row_start, cursor);
    fill_kernel<<<EE / 256, 256, 0, stream>>>(src, dst, ew, cursor, csr);

    // bn applied AFTER layer l: {bn1, bn1, bn2, bn3, bn3}
    const int bnsel[5] = {0, 0, 1, 2, 2};

    // layer 0
    aggregate<true><<<NN / 4, 256, 0, stream>>>(x, row_start, csr, h2buf);
    gemm_pair<64, false><<<NN / 64, 256, 0, stream>>>(
        h2buf, W1t[0], b1[0], W2t[0], b2[0],
        bg[0], bb[0], bm[0], bv[0], gidx, hA, pools, 0);

    const unsigned short* hin = hA;
    unsigned short* hout = hB;
    for (int l = 1; l < 5; ++l) {
        int s = bnsel[l];
        aggregate<false><<<NN / 4, 256, 0, stream>>>(hin, row_start, csr, h2buf);
        if (l < 4) {
            gemm_pair<128, false><<<NN / 64, 256, 0, stream>>>(
                h2buf, W1t[l], b1[l], W2t[l], b2[l],
                bg[s], bb[s], bm[s], bv[s], gidx, hout, pools, l * 128);
        } else {
            gemm_pair<128, true><<<NN / 64, 256, 0, stream>>>(
                h2buf, W1t[l], b1[l], W2t[l], b2[l],
                bg[s], bb[s], bm[s], bv[s], gidx, hout, pools, l * 128);
        }
        unsigned short* tmp = (unsigned short*)hin;
        hin = hout;
        hout = tmp;
    }

    readout<<<GG, 128, 0, stream>>>(pools, Wm1, bm1, Wm2, bm2, (float*)d_out);
}

// Round 5
// 433.028 us; speedup vs baseline: 1.8200x; 1.1714x over previous
//
#include <hip/hip_runtime.h>
#include <hip/hip_bf16.h>

#define NN 32768
#define EE 524288
#define GG 512

typedef __bf16 bf16x8 __attribute__((ext_vector_type(8)));
typedef float  f32x4  __attribute__((ext_vector_type(4)));

static __device__ __forceinline__ float bf2f(unsigned short u) {
    union { unsigned int i; float f; } v; v.i = ((unsigned int)u) << 16; return v.f;
}
static __device__ __forceinline__ unsigned short f2bf(float f) {
    __bf16 b = (__bf16)f;
    return __builtin_bit_cast(unsigned short, b);
}

// ---------------- fused convert_w + edge count ----------------
struct WJob { const float* in; unsigned short* out; int K; };
struct WJobs { WJob j[10]; };

__global__ __launch_bounds__(256) void prep_kernel(WJobs jobs, const int* __restrict__ src,
                                                   int* __restrict__ cnt) {
    if (blockIdx.x < 2048) {
        int e = blockIdx.x * 256 + threadIdx.x;
        atomicAdd(&cnt[src[e]], 1);
    } else {
        int b = blockIdx.x - 2048;
        WJob jb = jobs.j[b >> 2];
        int quarter = b & 3;
        int tot = jb.K * 128;
        int per = tot / 4;
        for (int idx = quarter * per + threadIdx.x; idx < (quarter + 1) * per; idx += 256) {
            int k = idx >> 7, c = idx & 127;
            jb.out[c * jb.K + k] = f2bf(jb.in[idx]);
        }
    }
}

// single block, 1024 threads; writes row_start AND cursor
__global__ void scan_kernel(const int* __restrict__ cnt, int* __restrict__ row_start,
                            int* __restrict__ cursor) {
    int tid = threadIdx.x;
    int base = tid * 32;
    int vals[32];
    int s = 0;
    #pragma unroll
    for (int i = 0; i < 32; ++i) { vals[i] = cnt[base + i]; s += vals[i]; }
    int lane = tid & 63, wave = tid >> 6;
    int incl = s;
    #pragma unroll
    for (int off = 1; off < 64; off <<= 1) {
        int t = __shfl_up(incl, off);
        if (lane >= off) incl += t;
    }
    __shared__ int wave_tot[16];
    if (lane == 63) wave_tot[wave] = incl;
    __syncthreads();
    int wave_base = 0;
    for (int w = 0; w < wave; ++w) wave_base += wave_tot[w];
    int run = wave_base + incl - s;
    #pragma unroll
    for (int i = 0; i < 32; ++i) {
        row_start[base + i] = run;
        cursor[base + i] = run;
        run += vals[i];
    }
    if (tid == 1023) row_start[NN] = run;
}

// packed CSR entry: low16 = dst node (<32768), high16 = bf16(edge weight)
__global__ void fill_kernel(const int* __restrict__ src, const int* __restrict__ dst,
                            const float* __restrict__ w,
                            int* __restrict__ cursor, unsigned int* __restrict__ csr) {
    int e = blockIdx.x * 256 + threadIdx.x;
    if (e < EE) {
        int s = src[e];
        int p = atomicAdd(&cursor[s], 1);
        csr[p] = (unsigned int)dst[e] | ((unsigned int)f2bf(w[e]) << 16);
    }
}

// ---------------- aggregation: one node per wave, 4 edges processed concurrently ----------------
// lanes split into 4 groups of 16; group g handles edge 4t+g with uint4 (16B) row-segment loads.
// h2[i] = h[i] + sum_{e: src=i} w_e * h[dst_e]   (bf16 out)
template<bool FIRST>
__global__ __launch_bounds__(256) void aggregate(const void* __restrict__ h_in,
                                                 const int* __restrict__ row_start,
                                                 const unsigned int* __restrict__ csr,
                                                 unsigned short* __restrict__ h2) {
    int node = blockIdx.x * 4 + (threadIdx.x >> 6);
    int lane = threadIdx.x & 63;
    int grp = lane >> 4, sub = lane & 15;
    int s = row_start[node], e = row_start[node + 1];

    if (FIRST) {   // fp32 input [N][64] = [N][16] float4; 4 channels per lane
        const float4* hp = (const float4*)h_in;
        float acc[4] = {0.f, 0.f, 0.f, 0.f};
        for (int base = s; base < e; base += 64) {
            int n = e - base; if (n > 64) n = 64;
            unsigned int ev = 0;
            if (lane < n) ev = csr[base + lane];
            int iters = (n + 3) >> 2;
            #pragma unroll 4
            for (int t = 0; t < iters; ++t) {
                unsigned int e2 = (unsigned int)__shfl((int)ev, 4 * t + grp);  // OOB lanes hold 0 -> w=0
                int d = e2 & 0xffff;
                float w = bf2f((unsigned short)(e2 >> 16));
                float4 hv = hp[d * 16 + sub];
                acc[0] += w * hv.x; acc[1] += w * hv.y;
                acc[2] += w * hv.z; acc[3] += w * hv.w;
            }
        }
        #pragma unroll
        for (int c = 0; c < 4; ++c) {
            acc[c] += __shfl_xor(acc[c], 16);
            acc[c] += __shfl_xor(acc[c], 32);
        }
        if (grp == 0) {
            float4 self = hp[node * 16 + sub];
            acc[0] += self.x; acc[1] += self.y; acc[2] += self.z; acc[3] += self.w;
            uint2 o;
            o.x = (unsigned int)f2bf(acc[0]) | ((unsigned int)f2bf(acc[1]) << 16);
            o.y = (unsigned int)f2bf(acc[2]) | ((unsigned int)f2bf(acc[3]) << 16);
            ((uint2*)h2)[node * 16 + sub] = o;
        }
    } else {       // bf16 input [N][128] = [N][16] uint4; 8 channels per lane
        const uint4* hp = (const uint4*)h_in;
        float acc[8];
        #pragma unroll
        for (int c = 0; c < 8; ++c) acc[c] = 0.f;
        for (int base = s; base < e; base += 64) {
            int n = e - base; if (n > 64) n = 64;
            unsigned int ev = 0;
            if (lane < n) ev = csr[base + lane];
            int iters = (n + 3) >> 2;
            #pragma unroll 4
            for (int t = 0; t < iters; ++t) {
                unsigned int e2 = (unsigned int)__shfl((int)ev, 4 * t + grp);
                int d = e2 & 0xffff;
                float w = bf2f((unsigned short)(e2 >> 16));
                uint4 hv = hp[d * 16 + sub];
                acc[0] += w * bf2f((unsigned short)(hv.x & 0xffff));
                acc[1] += w * bf2f((unsigned short)(hv.x >> 16));
                acc[2] += w * bf2f((unsigned short)(hv.y & 0xffff));
                acc[3] += w * bf2f((unsigned short)(hv.y >> 16));
                acc[4] += w * bf2f((unsigned short)(hv.z & 0xffff));
                acc[5] += w * bf2f((unsigned short)(hv.z >> 16));
                acc[6] += w * bf2f((unsigned short)(hv.w & 0xffff));
                acc[7] += w * bf2f((unsigned short)(hv.w >> 16));
            }
        }
        #pragma unroll
        for (int c = 0; c < 8; ++c) {
            acc[c] += __shfl_xor(acc[c], 16);
            acc[c] += __shfl_xor(acc[c], 32);
        }
        if (grp == 0) {
            uint4 self = hp[node * 16 + sub];
            acc[0] += bf2f((unsigned short)(self.x & 0xffff));
            acc[1] += bf2f((unsigned short)(self.x >> 16));
            acc[2] += bf2f((unsigned short)(self.y & 0xffff));
            acc[3] += bf2f((unsigned short)(self.y >> 16));
            acc[4] += bf2f((unsigned short)(self.z & 0xffff));
            acc[5] += bf2f((unsigned short)(self.z >> 16));
            acc[6] += bf2f((unsigned short)(self.w & 0xffff));
            acc[7] += bf2f((unsigned short)(self.w >> 16));
            uint4 o;
            o.x = (unsigned int)f2bf(acc[0]) | ((unsigned int)f2bf(acc[1]) << 16);
            o.y = (unsigned int)f2bf(acc[2]) | ((unsigned int)f2bf(acc[3]) << 16);
            o.z = (unsigned int)f2bf(acc[4]) | ((unsigned int)f2bf(acc[5]) << 16);
            o.w = (unsigned int)f2bf(acc[6]) | ((unsigned int)f2bf(acc[7]) << 16);
            ((uint4*)h2)[node * 16 + sub] = o;
        }
    }
}

// ---------------- fused GEMM pair + BN + pool ----------------
template<int K1, bool LAST>
__global__ __launch_bounds__(256, 2) void gemm_pair(
        const unsigned short* __restrict__ h2,    // [N][K1] bf16
        const unsigned short* __restrict__ W1t,   // [128][K1] bf16
        const float* __restrict__ b1,
        const unsigned short* __restrict__ W2t,   // [128][128] bf16
        const float* __restrict__ b2,
        const float* __restrict__ g, const float* __restrict__ be,
        const float* __restrict__ m, const float* __restrict__ v,
        const int* __restrict__ gidx,
        unsigned short* __restrict__ h_out,       // [N][128] bf16 (bn applied)
        float* __restrict__ pools, int col_off) {

    constexpr int A1W = K1 / 2 + 4;              // uints per A row
    __shared__ unsigned int smem[8704];          // A1 | T, overlaid later by OUT
    __shared__ float sscale[128], sshift[128];
    __shared__ int sgid[64];
    unsigned int* A1 = smem;
    unsigned int* T  = smem + 64 * A1W;
    float* OUT = (float*)smem;                   // [64][132] fp32

    int tid = threadIdx.x;
    int wave = tid >> 6, lane = tid & 63;

    if (tid < 128) {
        float sc = g[tid] * rsqrtf(v[tid] + 1e-3f);
        sscale[tid] = sc;
        sshift[tid] = be[tid] - m[tid] * sc;
    } else if (tid < 192) {
        sgid[tid - 128] = gidx[blockIdx.x * 64 + (tid - 128)];
    }

    // ---- stage A from global (coalesced) ----
    {
        int row = tid >> 2, q = tid & 3;
        const uint4* srcp = (const uint4*)((const unsigned int*)h2 +
                            (size_t)(blockIdx.x * 64 + row) * (K1 / 2)) + q * (K1 / 32);
        uint4* dstp = (uint4*)(A1 + row * A1W) + q * (K1 / 32);
        #pragma unroll
        for (int i = 0; i < K1 / 32; ++i) dstp[i] = srcp[i];
    }
    __syncthreads();

    // ---- GEMM1: T = relu(A1 @ W1 + b1) ----
    constexpr int KS1 = K1 / 32;
    int mrow = lane & 15, quad = lane >> 4;
    int myrow = wave * 16 + mrow;

    bf16x8 a1[KS1];
    #pragma unroll
    for (int kk = 0; kk < KS1; ++kk)
        a1[kk] = *(const bf16x8*)(A1 + myrow * A1W + kk * 16 + quad * 4);

    f32x4 acc1[8];
    #pragma unroll
    for (int c = 0; c < 8; ++c) acc1[c] = (f32x4){0.f, 0.f, 0.f, 0.f};
    #pragma unroll
    for (int c = 0; c < 8; ++c) {
        const bf16x8* Brow = (const bf16x8*)(W1t + (size_t)(c * 16 + mrow) * K1);
        #pragma unroll
        for (int kk = 0; kk < KS1; ++kk)
            acc1[c] = __builtin_amdgcn_mfma_f32_16x16x32_bf16(a1[kk], Brow[kk * 4 + quad], acc1[c], 0, 0, 0);
    }

    unsigned short* Tp = (unsigned short*)T;
    int rowbase = wave * 16 + quad * 4;
    #pragma unroll
    for (int c = 0; c < 8; ++c) {
        float bv = b1[c * 16 + mrow];
        #pragma unroll
        for (int r = 0; r < 4; ++r) {
            float val = fmaxf(acc1[c][r] + bv, 0.f);
            Tp[(rowbase + r) * 136 + c * 16 + mrow] = f2bf(val);
        }
    }
    __syncthreads();

    // ---- GEMM2: val = T @ W2 + b2 ----
    bf16x8 a2[4];
    #pragma unroll
    for (int kk = 0; kk < 4; ++kk)
        a2[kk] = *(const bf16x8*)(T + myrow * 68 + kk * 16 + quad * 4);

    f32x4 acc2[8];
    #pragma unroll
    for (int c = 0; c < 8; ++c) acc2[c] = (f32x4){0.f, 0.f, 0.f, 0.f};
    #pragma unroll
    for (int c = 0; c < 8; ++c) {
        const bf16x8* Brow = (const bf16x8*)(W2t + (size_t)(c * 16 + mrow) * 128);
        #pragma unroll
        for (int kk = 0; kk < 4; ++kk)
            acc2[c] = __builtin_amdgcn_mfma_f32_16x16x32_bf16(a2[kk], Brow[kk * 4 + quad], acc2[c], 0, 0, 0);
    }
    __syncthreads();   // all T reads done; OUT overlays A1/T

    #pragma unroll
    for (int c = 0; c < 8; ++c) {
        float bv = b2[c * 16 + mrow];
        #pragma unroll
        for (int r = 0; r < 4; ++r)
            OUT[(rowbase + r) * 132 + c * 16 + mrow] = acc2[c][r] + bv;
    }
    __syncthreads();

    // ---- h_out = bn(val) (coalesced, skip for LAST) ----
    if (!LAST) {
        int row = tid >> 2, q = tid & 3;
        const f32x4* Op = (const f32x4*)(OUT + row * 132 + q * 32);
        unsigned int pk[16];
        #pragma unroll
        for (int i = 0; i < 8; ++i) {
            f32x4 vv = Op[i];
            int c0 = q * 32 + i * 4;
            float o0 = vv[0] * sscale[c0 + 0] + sshift[c0 + 0];
            float o1 = vv[1] * sscale[c0 + 1] + sshift[c0 + 1];
            float o2 = vv[2] * sscale[c0 + 2] + sshift[c0 + 2];
            float o3 = vv[3] * sscale[c0 + 3] + sshift[c0 + 3];
            pk[i * 2]     = (unsigned int)f2bf(o0) | ((unsigned int)f2bf(o1) << 16);
            pk[i * 2 + 1] = (unsigned int)f2bf(o2) | ((unsigned int)f2bf(o3) << 16);
        }
        uint4* dstp = (uint4*)(h_out + (size_t)(blockIdx.x * 64 + row) * 128 + q * 32);
        #pragma unroll
        for (int i = 0; i < 4; ++i)
            dstp[i] = make_uint4(pk[i * 4], pk[i * 4 + 1], pk[i * 4 + 2], pk[i * 4 + 3]);
    }

    // ---- segmented pool ----
    {
        int col = tid & 127, half = tid >> 7;
        float sc = LAST ? sscale[col] : 1.f;
        float sh = LAST ? sshift[col] : 0.f;
        float acc = 0.f;
        int cur = sgid[half * 32];
        for (int r = half * 32; r < half * 32 + 32; ++r) {
            int gi = sgid[r];
            if (gi != cur) {
                atomicAdd(&pools[(size_t)cur * 640 + col_off + col], acc);
                acc = 0.f;
                cur = gi;
            }
            float val = OUT[r * 132 + col];
            acc += LAST ? (val * sc + sh) : val;
        }
        atomicAdd(&pools[(size_t)cur * 640 + col_off + col], acc);
    }
}

// ---------------- fused readout ----------------
__global__ __launch_bounds__(128) void readout(const float* __restrict__ pools,
                                               const float* __restrict__ Wm1,
                                               const float* __restrict__ bm1,
                                               const float* __restrict__ Wm2,
                                               const float* __restrict__ bm2,
                                               float* __restrict__ out) {
    __shared__ float row[640];
    __shared__ float partial[4];
    int gb = blockIdx.x;
    for (int k = threadIdx.x; k < 640; k += 128) row[k] = pools[(size_t)gb * 640 + k];
    __syncthreads();
    int j = threadIdx.x;
    float acc = bm1[j];
    for (int k = 0; k < 640; ++k) acc += row[k] * Wm1[(size_t)k * 128 + j];
    acc = fmaxf(acc, 0.f);
    float p0 = acc * Wm2[j * 2], p1 = acc * Wm2[j * 2 + 1];
    #pragma unroll
    for (int off = 32; off; off >>= 1) { p0 += __shfl_down(p0, off); p1 += __shfl_down(p1, off); }
    int wave = j >> 6;
    if ((j & 63) == 0) { partial[wave * 2] = p0; partial[wave * 2 + 1] = p1; }
    __syncthreads();
    if (j == 0) {
        out[gb * 2]     = bm2[0] + partial[0] + partial[2];
        out[gb * 2 + 1] = bm2[1] + partial[1] + partial[3];
    }
}

extern "C" void kernel_launch(void* const* d_in, const int* in_sizes, int n_in,
                              void* d_out, int out_size, void* d_ws, size_t ws_size,
                              hipStream_t stream) {
    const float* x  = (const float*)d_in[0];
    const float* ew = (const float*)d_in[1];
    const float *W1[5], *b1[5], *W2[5], *b2[5];
    for (int l = 0; l < 5; ++l) {
        W1[l] = (const float*)d_in[2 + 4 * l];
        b1[l] = (const float*)d_in[3 + 4 * l];
        W2[l] = (const float*)d_in[4 + 4 * l];
        b2[l] = (const float*)d_in[5 + 4 * l];
    }
    const float *bg[3], *bb[3], *bm[3], *bv[3];
    for (int j = 0; j < 3; ++j) {
        bg[j] = (const float*)d_in[22 + 4 * j];
        bb[j] = (const float*)d_in[23 + 4 * j];
        bm[j] = (const float*)d_in[24 + 4 * j];
        bv[j] = (const float*)d_in[25 + 4 * j];
    }
    const float* Wm1 = (const float*)d_in[34];
    const float* bm1 = (const float*)d_in[35];
    const float* Wm2 = (const float*)d_in[36];
    const float* bm2 = (const float*)d_in[37];
    const int* edge_index = (const int*)d_in[38];
    const int* src = edge_index;
    const int* dst = edge_index + EE;
    const int* gidx = (const int*)d_in[39];

    char* p = (char*)d_ws;
    auto alloc = [&](size_t bytes) -> void* {
        void* r = (void*)p;
        p += (bytes + 255) & ~(size_t)255;
        return r;
    };
    unsigned int* csr = (unsigned int*)alloc((size_t)EE * 4);
    int* row_start    = (int*)alloc((NN + 1) * 4);
    int* cnt          = (int*)alloc(NN * 4);
    int* cursor       = (int*)alloc(NN * 4);
    unsigned short* h2buf = (unsigned short*)alloc((size_t)NN * 128 * 2);
    unsigned short* hA    = (unsigned short*)alloc((size_t)NN * 128 * 2);
    unsigned short* hB    = (unsigned short*)alloc((size_t)NN * 128 * 2);
    float* pools = (float*)alloc((size_t)GG * 640 * 4);
    unsigned short* W1t[5], *W2t[5];
    for (int l = 0; l < 5; ++l) {
        W1t[l] = (unsigned short*)alloc((size_t)128 * 128 * 2);
        W2t[l] = (unsigned short*)alloc((size_t)128 * 128 * 2);
    }

    hipMemsetAsync(cnt, 0, NN * 4, stream);
    hipMemsetAsync(pools, 0, (size_t)GG * 640 * 4, stream);

    WJobs jobs;
    for (int l = 0; l < 5; ++l) {
        jobs.j[2 * l]     = WJob{W1[l], W1t[l], (l == 0) ? 64 : 128};
        jobs.j[2 * l + 1] = WJob{W2[l], W2t[l], 128};
    }
    prep_kernel<<<2048 + 40, 256, 0, stream>>>(jobs, src, cnt);
    scan_kernel<<<1, 1024, 0, stream>>>(cnt, row_start, cursor);
    fill_kernel<<<EE / 256, 256, 0, stream>>>(src, dst, ew, cursor, csr);

    // bn applied AFTER layer l: {bn1, bn1, bn2, bn3, bn3}
    const int bnsel[5] = {0, 0, 1, 2, 2};

    // layer 0
    aggregate<true><<<NN / 4, 256, 0, stream>>>(x, row_start, csr, h2buf);
    gemm_pair<64, false><<<NN / 64, 256, 0, stream>>>(
        h2buf, W1t[0], b1[0], W2t[0], b2[0],
        bg[0], bb[0], bm[0], bv[0], gidx, hA, pools, 0);

    const unsigned short* hin = hA;
    unsigned short* hout = hB;
    for (int l = 1; l < 5; ++l) {
        int s = bnsel[l];
        aggregate<false><<<NN / 4, 256, 0, stream>>>(hin, row_start, csr, h2buf);
        if (l < 4) {
            gemm_pair<128, false><<<NN / 64, 256, 0, stream>>>(
                h2buf, W1t[l], b1[l], W2t[l], b2[l],
                bg[s], bb[s], bm[s], bv[s], gidx, hout, pools, l * 128);
        } else {
            gemm_pair<128, true><<<NN / 64, 256, 0, stream>>>(
                h2buf, W1t[l], b1[l], W2t[l], b2[l],
                bg[s], bb[s], bm[s], bv[s], gidx, hout, pools, l * 128);
        }
        unsigned short* tmp = (unsigned short*)hin;
        hin = hout;
        hout = tmp;
    }

    readout<<<GG, 128, 0, stream>>>(pools, Wm1, bm1, Wm2, bm2, (float*)d_out);
}

// Round 7
// 394.745 us; speedup vs baseline: 1.9965x; 1.0970x over previous
//
#include <hip/hip_runtime.h>
#include <hip/hip_bf16.h>

#define NN 32768
#define EE 524288
#define GG 512

typedef __bf16 bf16x8 __attribute__((ext_vector_type(8)));
typedef float  f32x4  __attribute__((ext_vector_type(4)));

static __device__ __forceinline__ float bf2f(unsigned short u) {
    union { unsigned int i; float f; } v; v.i = ((unsigned int)u) << 16; return v.f;
}
static __device__ __forceinline__ unsigned short f2bf(float f) {
    __bf16 b = (__bf16)f;
    return __builtin_bit_cast(unsigned short, b);
}
static __device__ __forceinline__ unsigned int pk2(float a, float b) {
    return (unsigned int)f2bf(a) | ((unsigned int)f2bf(b) << 16);
}

// ---------------- fused convert_w + edge count ----------------
struct WJob { const float* in; unsigned short* out; int K; };
struct WJobs { WJob j[10]; };

__global__ __launch_bounds__(256) void prep_kernel(WJobs jobs, const int* __restrict__ src,
                                                   int* __restrict__ cnt) {
    if (blockIdx.x < 2048) {
        int e = blockIdx.x * 256 + threadIdx.x;
        atomicAdd(&cnt[src[e]], 1);
    } else {
        int b = blockIdx.x - 2048;
        WJob jb = jobs.j[b >> 2];
        int quarter = b & 3;
        int per = jb.K * 128 / 4;
        for (int idx = quarter * per + threadIdx.x; idx < (quarter + 1) * per; idx += 256) {
            int k = idx >> 7, c = idx & 127;
            jb.out[c * jb.K + k] = f2bf(jb.in[idx]);
        }
    }
}

// single block, 1024 threads; writes row_start AND cursor
__global__ void scan_kernel(const int* __restrict__ cnt, int* __restrict__ row_start,
                            int* __restrict__ cursor) {
    int tid = threadIdx.x;
    int base = tid * 32;
    int vals[32];
    int s = 0;
    #pragma unroll
    for (int i = 0; i < 32; ++i) { vals[i] = cnt[base + i]; s += vals[i]; }
    int lane = tid & 63, wave = tid >> 6;
    int incl = s;
    #pragma unroll
    for (int off = 1; off < 64; off <<= 1) {
        int t = __shfl_up(incl, off);
        if (lane >= off) incl += t;
    }
    __shared__ int wave_tot[16];
    if (lane == 63) wave_tot[wave] = incl;
    __syncthreads();
    int wave_base = 0;
    for (int w = 0; w < wave; ++w) wave_base += wave_tot[w];
    int run = wave_base + incl - s;
    #pragma unroll
    for (int i = 0; i < 32; ++i) {
        row_start[base + i] = run;
        cursor[base + i] = run;
        run += vals[i];
    }
    if (tid == 1023) row_start[NN] = run;
}

// packed CSR entry: low16 = dst node (<32768), high16 = bf16(edge weight)
__global__ void fill_kernel(const int* __restrict__ src, const int* __restrict__ dst,
                            const float* __restrict__ w,
                            int* __restrict__ cursor, unsigned int* __restrict__ csr) {
    int e = blockIdx.x * 256 + threadIdx.x;
    if (e < EE) {
        int s = src[e];
        int p = atomicAdd(&cursor[s], 1);
        csr[p] = (unsigned int)dst[e] | ((unsigned int)f2bf(w[e]) << 16);
    }
}

// ---------------- fused GIN layer: gather + GEMM1 + GEMM2 + BN + pool ----------------
// 2048 blocks x 256 thr (4 waves). Block owns 16 nodes/rows.
// Gather: wave w handles nodes w*4..w*4+3, 4 concurrent 16-lane edge streams.
// GEMM: wave w computes cols w*32..w*32+31 (two 16x16 col-tiles) over all 16 rows.
template<bool FIRST, bool LAST>
__global__ __launch_bounds__(256) void layer_kernel(
        const void* __restrict__ h_in,            // FIRST: fp32 [N][64], else bf16 [N][128]
        const int* __restrict__ row_start,
        const unsigned int* __restrict__ csr,
        const unsigned short* __restrict__ W1t,   // [128][K1] bf16
        const float* __restrict__ b1,
        const unsigned short* __restrict__ W2t,   // [128][128] bf16
        const float* __restrict__ b2,
        const float* __restrict__ g, const float* __restrict__ be,
        const float* __restrict__ m, const float* __restrict__ v,
        const int* __restrict__ gidx,
        unsigned short* __restrict__ h_out,       // [N][128] bf16 bn'd (unused if LAST)
        float* __restrict__ pools, int col_off) {

    constexpr int K1 = FIRST ? 64 : 128;
    constexpr int KS1 = K1 / 32;

    __shared__ unsigned int smem[2176];       // A1[16][68] | T[16][68]; OUT[16][132] overlays
    __shared__ float sscale[128], sshift[128];
    __shared__ int sgid[16];

    unsigned int* A1 = smem;
    unsigned int* T  = smem + 16 * 68;
    float* OUT = (float*)smem;

    int tid = threadIdx.x;
    int wave = tid >> 6, lane = tid & 63;
    int grp = lane >> 4, sub = lane & 15;     // gather roles
    int mrow = lane & 15, quad = lane >> 4;   // mfma roles

    if (tid < 128) {
        float sc = g[tid] * rsqrtf(v[tid] + 1e-3f);
        sscale[tid] = sc;
        sshift[tid] = be[tid] - m[tid] * sc;
    } else if (tid < 144) {
        sgid[tid - 128] = gidx[blockIdx.x * 16 + (tid - 128)];
    }

    // ---- gather into A1 ----
    if (FIRST) {
        const float4* hp = (const float4*)h_in;
        for (int i = 0; i < 4; ++i) {
            int r = wave * 4 + i;
            int node = blockIdx.x * 16 + r;
            int s = row_start[node], e = row_start[node + 1];
            float ac0 = 0.f, ac1 = 0.f, ac2 = 0.f, ac3 = 0.f;
            for (int base = s; base < e; base += 64) {
                int n = e - base; if (n > 64) n = 64;
                unsigned int ev = (lane < n) ? csr[base + lane] : 0u;
                int iters = (n + 3) >> 2;
                #pragma unroll 4
                for (int t = 0; t < iters; ++t) {
                    unsigned int e2 = (unsigned int)__shfl((int)ev, 4 * t + grp);
                    float w = bf2f((unsigned short)(e2 >> 16));
                    float4 hv = hp[(e2 & 0xffffu) * 16 + sub];
                    ac0 += w * hv.x; ac1 += w * hv.y; ac2 += w * hv.z; ac3 += w * hv.w;
                }
            }
            ac0 += __shfl_xor(ac0, 16); ac0 += __shfl_xor(ac0, 32);
            ac1 += __shfl_xor(ac1, 16); ac1 += __shfl_xor(ac1, 32);
            ac2 += __shfl_xor(ac2, 16); ac2 += __shfl_xor(ac2, 32);
            ac3 += __shfl_xor(ac3, 16); ac3 += __shfl_xor(ac3, 32);
            if (grp == 0) {
                float4 self = hp[(size_t)node * 16 + sub];
                ac0 += self.x; ac1 += self.y; ac2 += self.z; ac3 += self.w;
                *(uint2*)(A1 + r * 68 + sub * 2) = make_uint2(pk2(ac0, ac1), pk2(ac2, ac3));
            }
        }
    } else {
        const uint4* hp = (const uint4*)h_in;
        for (int i = 0; i < 4; ++i) {
            int r = wave * 4 + i;
            int node = blockIdx.x * 16 + r;
            int s = row_start[node], e = row_start[node + 1];
            float acc[8];
            #pragma unroll
            for (int c = 0; c < 8; ++c) acc[c] = 0.f;
            for (int base = s; base < e; base += 64) {
                int n = e - base; if (n > 64) n = 64;
                unsigned int ev = (lane < n) ? csr[base + lane] : 0u;
                int iters = (n + 3) >> 2;
                #pragma unroll 4
                for (int t = 0; t < iters; ++t) {
                    unsigned int e2 = (unsigned int)__shfl((int)ev, 4 * t + grp);
                    float w = bf2f((unsigned short)(e2 >> 16));
                    uint4 hv = hp[(e2 & 0xffffu) * 16 + sub];
                    acc[0] += w * bf2f((unsigned short)(hv.x & 0xffff));
                    acc[1] += w * bf2f((unsigned short)(hv.x >> 16));
                    acc[2] += w * bf2f((unsigned short)(hv.y & 0xffff));
                    acc[3] += w * bf2f((unsigned short)(hv.y >> 16));
                    acc[4] += w * bf2f((unsigned short)(hv.z & 0xffff));
                    acc[5] += w * bf2f((unsigned short)(hv.z >> 16));
                    acc[6] += w * bf2f((unsigned short)(hv.w & 0xffff));
                    acc[7] += w * bf2f((unsigned short)(hv.w >> 16));
                }
            }
            #pragma unroll
            for (int c = 0; c < 8; ++c) {
                acc[c] += __shfl_xor(acc[c], 16);
                acc[c] += __shfl_xor(acc[c], 32);
            }
            if (grp == 0) {
                uint4 self = hp[(size_t)node * 16 + sub];
                acc[0] += bf2f((unsigned short)(self.x & 0xffff));
                acc[1] += bf2f((unsigned short)(self.x >> 16));
                acc[2] += bf2f((unsigned short)(self.y & 0xffff));
                acc[3] += bf2f((unsigned short)(self.y >> 16));
                acc[4] += bf2f((unsigned short)(self.z & 0xffff));
                acc[5] += bf2f((unsigned short)(self.z >> 16));
                acc[6] += bf2f((unsigned short)(self.w & 0xffff));
                acc[7] += bf2f((unsigned short)(self.w >> 16));
                *(uint4*)(A1 + r * 68 + sub * 4) =
                    make_uint4(pk2(acc[0], acc[1]), pk2(acc[2], acc[3]),
                               pk2(acc[4], acc[5]), pk2(acc[6], acc[7]));
            }
        }
    }
    __syncthreads();

    // ---- GEMM1: T = relu(A1 @ W1 + b1); wave computes cols wave*32..+31 ----
    const unsigned short* A1s = (const unsigned short*)A1;
    unsigned short* Ts = (unsigned short*)T;

    bf16x8 af[KS1];
    #pragma unroll
    for (int kk = 0; kk < KS1; ++kk)
        af[kk] = *(const bf16x8*)(A1s + mrow * 136 + kk * 32 + quad * 8);

    f32x4 acc1v[2];
    #pragma unroll
    for (int c = 0; c < 2; ++c) acc1v[c] = (f32x4){0.f, 0.f, 0.f, 0.f};
    #pragma unroll
    for (int c = 0; c < 2; ++c) {
        const bf16x8* Brow = (const bf16x8*)(W1t + (size_t)(wave * 32 + c * 16 + mrow) * K1);
        #pragma unroll
        for (int kk = 0; kk < KS1; ++kk)
            acc1v[c] = __builtin_amdgcn_mfma_f32_16x16x32_bf16(af[kk], Brow[kk * 4 + quad], acc1v[c], 0, 0, 0);
    }
    #pragma unroll
    for (int c = 0; c < 2; ++c) {
        int ocol = wave * 32 + c * 16 + mrow;
        float bv = b1[ocol];
        #pragma unroll
        for (int r = 0; r < 4; ++r)
            Ts[(quad * 4 + r) * 136 + ocol] = f2bf(fmaxf(acc1v[c][r] + bv, 0.f));
    }
    __syncthreads();

    // ---- GEMM2: val = T @ W2 + b2 ----
    bf16x8 a2f[4];
    #pragma unroll
    for (int kk = 0; kk < 4; ++kk)
        a2f[kk] = *(const bf16x8*)(Ts + mrow * 136 + kk * 32 + quad * 8);
    f32x4 acc2v[2];
    #pragma unroll
    for (int c = 0; c < 2; ++c) acc2v[c] = (f32x4){0.f, 0.f, 0.f, 0.f};
    #pragma unroll
    for (int c = 0; c < 2; ++c) {
        const bf16x8* Brow = (const bf16x8*)(W2t + (size_t)(wave * 32 + c * 16 + mrow) * 128);
        #pragma unroll
        for (int kk = 0; kk < 4; ++kk)
            acc2v[c] = __builtin_amdgcn_mfma_f32_16x16x32_bf16(a2f[kk], Brow[kk * 4 + quad], acc2v[c], 0, 0, 0);
    }
    __syncthreads();     // T reads done; OUT overlays A1/T

    #pragma unroll
    for (int c = 0; c < 2; ++c) {
        int ocol = wave * 32 + c * 16 + mrow;
        float bv = b2[ocol];
        #pragma unroll
        for (int r = 0; r < 4; ++r)
            OUT[(quad * 4 + r) * 132 + ocol] = acc2v[c][r] + bv;
    }
    __syncthreads();

    // ---- h_out = bn(val), bf16, coalesced (not for LAST) ----
    if (!LAST) {
        int row = tid >> 4, q = tid & 15;    // 16 rows x 16 col-groups of 8
        const float* Op = OUT + row * 132 + q * 8;
        unsigned int pk[4];
        #pragma unroll
        for (int i = 0; i < 4; ++i) {
            int c0 = q * 8 + i * 2;
            float o0 = Op[i * 2]     * sscale[c0]     + sshift[c0];
            float o1 = Op[i * 2 + 1] * sscale[c0 + 1] + sshift[c0 + 1];
            pk[i] = pk2(o0, o1);
        }
        *(uint4*)(h_out + (size_t)(blockIdx.x * 16 + row) * 128 + q * 8) =
            make_uint4(pk[0], pk[1], pk[2], pk[3]);
    }

    // ---- segmented pool (LAST pools bn'd values) ----
    {
        int col = tid & 127, half = tid >> 7;
        float sc = LAST ? sscale[col] : 1.f;
        float sh = LAST ? sshift[col] : 0.f;
        float accp = 0.f;
        int cur = sgid[half * 8];
        for (int r = half * 8; r < half * 8 + 8; ++r) {
            int gi = sgid[r];
            if (gi != cur) {
                atomicAdd(&pools[(size_t)cur * 640 + col_off + col], accp);
                accp = 0.f;
                cur = gi;
            }
            float val = OUT[r * 132 + col];
            accp += LAST ? (val * sc + sh) : val;
        }
        atomicAdd(&pools[(size_t)cur * 640 + col_off + col], accp);
    }
}

// ---------------- fused readout ----------------
__global__ __launch_bounds__(128) void readout(const float* __restrict__ pools,
                                               const float* __restrict__ Wm1,
                                               const float* __restrict__ bm1,
                                               const float* __restrict__ Wm2,
                                               const float* __restrict__ bm2,
                                               float* __restrict__ out) {
    __shared__ float row[640];
    __shared__ float partial[4];
    int gb = blockIdx.x;
    for (int k = threadIdx.x; k < 640; k += 128) row[k] = pools[(size_t)gb * 640 + k];
    __syncthreads();
    int j = threadIdx.x;
    float acc = bm1[j];
    for (int k = 0; k < 640; ++k) acc += row[k] * Wm1[(size_t)k * 128 + j];
    acc = fmaxf(acc, 0.f);
    float p0 = acc * Wm2[j * 2], p1 = acc * Wm2[j * 2 + 1];
    #pragma unroll
    for (int off = 32; off; off >>= 1) { p0 += __shfl_down(p0, off); p1 += __shfl_down(p1, off); }
    int wave = j >> 6;
    if ((j & 63) == 0) { partial[wave * 2] = p0; partial[wave * 2 + 1] = p1; }
    __syncthreads();
    if (j == 0) {
        out[gb * 2]     = bm2[0] + partial[0] + partial[2];
        out[gb * 2 + 1] = bm2[1] + partial[1] + partial[3];
    }
}

extern "C" void kernel_launch(void* const* d_in, const int* in_sizes, int n_in,
                              void* d_out, int out_size, void* d_ws, size_t ws_size,
                              hipStream_t stream) {
    const float* x  = (const float*)d_in[0];
    const float* ew = (const float*)d_in[1];
    const float *W1[5], *b1[5], *W2[5], *b2[5];
    for (int l = 0; l < 5; ++l) {
        W1[l] = (const float*)d_in[2 + 4 * l];
        b1[l] = (const float*)d_in[3 + 4 * l];
        W2[l] = (const float*)d_in[4 + 4 * l];
        b2[l] = (const float*)d_in[5 + 4 * l];
    }
    const float *bg[3], *bb[3], *bm[3], *bv[3];
    for (int j = 0; j < 3; ++j) {
        bg[j] = (const float*)d_in[22 + 4 * j];
        bb[j] = (const float*)d_in[23 + 4 * j];
        bm[j] = (const float*)d_in[24 + 4 * j];
        bv[j] = (const float*)d_in[25 + 4 * j];
    }
    const float* Wm1 = (const float*)d_in[34];
    const float* bm1 = (const float*)d_in[35];
    const float* Wm2 = (const float*)d_in[36];
    const float* bm2 = (const float*)d_in[37];
    const int* edge_index = (const int*)d_in[38];
    const int* src = edge_index;
    const int* dst = edge_index + EE;
    const int* gidx = (const int*)d_in[39];

    char* p = (char*)d_ws;
    auto alloc = [&](size_t bytes) -> void* {
        void* r = (void*)p;
        p += (bytes + 255) & ~(size_t)255;
        return r;
    };
    unsigned int* csr = (unsigned int*)alloc((size_t)EE * 4);
    int* row_start    = (int*)alloc((NN + 1) * 4);
    int* cnt          = (int*)alloc(NN * 4);
    int* cursor       = (int*)alloc(NN * 4);
    unsigned short* hA = (unsigned short*)alloc((size_t)NN * 128 * 2);
    unsigned short* hB = (unsigned short*)alloc((size_t)NN * 128 * 2);
    float* pools = (float*)alloc((size_t)GG * 640 * 4);
    unsigned short* W1t[5], *W2t[5];
    for (int l = 0; l < 5; ++l) {
        W1t[l] = (unsigned short*)alloc((size_t)128 * 128 * 2);
        W2t[l] = (unsigned short*)alloc((size_t)128 * 128 * 2);
    }

    hipMemsetAsync(cnt, 0, NN * 4, stream);
    hipMemsetAsync(pools, 0, (size_t)GG * 640 * 4, stream);

    WJobs jobs;
    for (int l = 0; l < 5; ++l) {
        jobs.j[2 * l]     = WJob{W1[l], W1t[l], (l == 0) ? 64 : 128};
        jobs.j[2 * l + 1] = WJob{W2[l], W2t[l], 128};
    }
    prep_kernel<<<2048 + 40, 256, 0, stream>>>(jobs, src, cnt);
    scan_kernel<<<1, 1024, 0, stream>>>(cnt, row_start, cursor);
    fill_kernel<<<EE / 256, 256, 0, stream>>>(src, dst, ew, cursor, csr);

    // bn applied AFTER layer l: {bn1, bn1, bn2, bn3, bn3}
    const int bnsel[5] = {0, 0, 1, 2, 2};

    // layer 0 (fp32 x input)
    layer_kernel<true, false><<<NN / 16, 256, 0, stream>>>(
        x, row_start, csr, W1t[0], b1[0], W2t[0], b2[0],
        bg[0], bb[0], bm[0], bv[0], gidx, hA, pools, 0);

    const unsigned short* hin = hA;
    unsigned short* hout = hB;
    for (int l = 1; l < 5; ++l) {
        int s = bnsel[l];
        if (l < 4) {
            layer_kernel<false, false><<<NN / 16, 256, 0, stream>>>(
                hin, row_start, csr, W1t[l], b1[l], W2t[l], b2[l],
                bg[s], bb[s], bm[s], bv[s], gidx, hout, pools, l * 128);
        } else {
            layer_kernel<false, true><<<NN / 16, 256, 0, stream>>>(
                hin, row_start, csr, W1t[l], b1[l], W2t[l], b2[l],
                bg[s], bb[s], bm[s], bv[s], gidx, hout, pools, l * 128);
        }
        unsigned short* tmp = (unsigned short*)hin;
        hin = hout;
        hout = tmp;
    }

    readout<<<GG, 128, 0, stream>>>(pools, Wm1, bm1, Wm2, bm2, (float*)d_out);
}